// Round 1
// baseline (164.306 us; speedup 1.0000x reference)
//
#include <hip/hip_runtime.h>
#include <stdint.h>

// Problem: BahdanauAttention  H=512, L=2, B=64, T=2048
// scores[t,b] = Wo . tanh( enc[t,b,:] @ We^T + comb[b,:] )   (bo dropped: softmax-invariant)
// comb[b,:]   = mean_l(hidden[l,b,:]) @ Wh^T + bh + be
// out[b,t]    = masked softmax over t < enc_len[b]
//
// Workspace layout (needs 1,179,648 B):
//   [0, 512K)            : We packed bf16, 8 K-slices of 64KB, swizzled LDS image
//   [512K, 512K+128K)    : comb f32 [64][512]
//   [640K, 640K+512K)    : scores f32 [64][2048]  (b-major for softmax)

typedef __attribute__((ext_vector_type(4))) float f32x4;
typedef __attribute__((ext_vector_type(8))) __bf16 bf16x8;
typedef __attribute__((ext_vector_type(8))) unsigned short u16x8;

#define AS3 __attribute__((address_space(3)))
#define AS1 __attribute__((address_space(1)))

__device__ __forceinline__ unsigned short f2bf(float f) {
  unsigned u = __builtin_bit_cast(unsigned, f);
  return (unsigned short)((u + 0x7FFFu + ((u >> 16) & 1u)) >> 16);  // RNE
}

__device__ __forceinline__ float fast_tanh(float x) {
  float t = __expf(-2.0f * __builtin_fabsf(x));
  float r = (1.0f - t) * __builtin_amdgcn_rcpf(1.0f + t);
  return __builtin_copysignf(r, x);
}

// ---------------- prep 1: comb[b,o] = mean_l hidden @ Wh^T + bh + be ----------
__global__ void prep_comb_kernel(const float* __restrict__ hidden,
                                 const float* __restrict__ Wh,
                                 const float* __restrict__ bh,
                                 const float* __restrict__ be,
                                 float* __restrict__ comb) {
  __shared__ float hb[512];
  const int b = blockIdx.x, tid = threadIdx.x;  // 256 threads
  for (int i = tid; i < 512; i += 256)
    hb[i] = 0.5f * (hidden[b * 512 + i] + hidden[32768 + b * 512 + i]);
  __syncthreads();
  for (int o = tid; o < 512; o += 256) {
    const f32x4* wr = (const f32x4*)(Wh + o * 512);
    const f32x4* hv = (const f32x4*)hb;
    float s = 0.f;
    for (int k = 0; k < 128; ++k) {
      f32x4 w = wr[k], x = hv[k];
      s += w.x * x.x + w.y * x.y + w.z * x.z + w.w * x.w;
    }
    comb[b * 512 + o] = s + bh[o] + be[o];
  }
}

// ---------------- prep 2: pack We -> bf16 swizzled K-slice LDS images --------
// Slice s (k0 = s*64) is a 64KB image: byte addr within slice =
//   o*128 + ((g ^ (o&7)) * 16),  content = bf16(We[o][k0 + g*8 .. +8])
__global__ void prep_pack_kernel(const float* __restrict__ We,
                                 unsigned short* __restrict__ wsw) {
  const int gid = blockIdx.x * 256 + threadIdx.x;  // 0..32767
  const int s = gid >> 12;
  const int idx = gid & 4095;
  const int o = idx >> 3;
  const int sp = idx & 7;
  const int g = sp ^ (o & 7);
  const float* src = We + o * 512 + s * 64 + g * 8;
  u16x8 p;
#pragma unroll
  for (int e = 0; e < 8; ++e) p[e] = f2bf(src[e]);
  *(u16x8*)(wsw + (long)gid * 8) = p;
}

// ---------------- main: fused GEMM + tanh + Wo-dot -> scores -----------------
// grid 2048 (one block per t), 512 threads (8 waves: wm in {0,1}, wn in {0..3})
// block tile: 64 rows (all b of one t) x 512 cols, BK=64, mfma 16x16x32 bf16
__global__ __launch_bounds__(512, 4) void gemm_score_kernel(
    const float* __restrict__ enc,            // [T*B, 512] (row = t*64+b)
    const unsigned short* __restrict__ wsw,   // packed We
    const float* __restrict__ comb,           // [64,512]
    const float* __restrict__ Wo,             // [512]
    float* __restrict__ scores)               // [64,2048]
{
  __shared__ __align__(16) unsigned char Blds[65536];   // 512 o x 64 k bf16 (swizzled)
  __shared__ __align__(16) unsigned char Alds[64 * 144]; // 64 rows x 64 k bf16, stride 144B
  __shared__ float spart[4][64];

  const int tid = threadIdx.x;
  const int lane = tid & 63;
  const int wave = tid >> 6;
  const int wm = wave >> 2;   // row half
  const int wn = wave & 3;    // col quarter
  const int l15 = lane & 15;
  const int lq = lane >> 4;   // 0..3

  const long r0 = (long)blockIdx.x * 64;

  // A staging: thread loads 8 f32 of one row per K-step
  const int arow = tid >> 3;
  const int ak8 = tid & 7;
  const float* aglb = enc + (r0 + arow) * 512 + ak8 * 8;
  unsigned char* awr = &Alds[arow * 144 + ak8 * 16];

  const unsigned char* bglb = (const unsigned char*)wsw + (long)tid * 16;

  // fragment read offsets
  const unsigned aoff0 = (unsigned)((wm * 32 + l15) * 144 + lq * 16);
  const int obase = wn * 128 + l15;
  const int o7 = l15 & 7;

  f32x4 acc[2][8];
#pragma unroll
  for (int i = 0; i < 2; ++i)
#pragma unroll
    for (int j = 0; j < 8; ++j) acc[i][j] = (f32x4){0.f, 0.f, 0.f, 0.f};

  f32x4 av0 = *(const f32x4*)(aglb);
  f32x4 av1 = *(const f32x4*)(aglb + 4);

  for (int ks = 0; ks < 8; ++ks) {
    // stage B tile (linear LDS image, pre-swizzled in global)
    const unsigned char* bs = bglb + (long)ks * 65536;
#pragma unroll
    for (int c = 0; c < 8; ++c) {
      __builtin_amdgcn_global_load_lds((const AS1 unsigned int*)(bs + c * 8192),
                                       (AS3 unsigned int*)(&Blds[tid * 16 + c * 8192]),
                                       16, 0, 0);
    }
    // stage A tile (cvt f32->bf16, one 16B LDS store)
    u16x8 p;
    p[0] = f2bf(av0.x); p[1] = f2bf(av0.y); p[2] = f2bf(av0.z); p[3] = f2bf(av0.w);
    p[4] = f2bf(av1.x); p[5] = f2bf(av1.y); p[6] = f2bf(av1.z); p[7] = f2bf(av1.w);
    *(u16x8*)awr = p;
    __syncthreads();  // drains global_load_lds + ds_write

    if (ks < 7) {  // prefetch next A during compute; drained at next barrier
      av0 = *(const f32x4*)(aglb + (ks + 1) * 64);
      av1 = *(const f32x4*)(aglb + (ks + 1) * 64 + 4);
    }

#pragma unroll
    for (int ksub = 0; ksub < 2; ++ksub) {
      bf16x8 af0 = *(const bf16x8*)(&Alds[aoff0 + ksub * 64]);
      bf16x8 af1 = *(const bf16x8*)(&Alds[aoff0 + 16 * 144 + ksub * 64]);
#pragma unroll
      for (int jn = 0; jn < 8; ++jn) {
        const int o = obase + jn * 16;
        const int g = ksub * 4 + lq;
        bf16x8 bf = *(const bf16x8*)(&Blds[o * 128 + ((g ^ o7) << 4)]);
        acc[0][jn] = __builtin_amdgcn_mfma_f32_16x16x32_bf16(af0, bf, acc[0][jn], 0, 0, 0);
        acc[1][jn] = __builtin_amdgcn_mfma_f32_16x16x32_bf16(af1, bf, acc[1][jn], 0, 0, 0);
      }
    }
    __syncthreads();
  }

  // ---- fused epilogue: tanh(acc + comb[b,col]) * Wo[col], reduce over cols ----
  // D frag: row = lq*4 + q (+i*16 +wm*32), col = l15 (+jn*16 +wn*128). b == local row.
  float ps[2][4];
#pragma unroll
  for (int i = 0; i < 2; ++i) {
#pragma unroll
    for (int q = 0; q < 4; ++q) {
      const int row = wm * 32 + i * 16 + lq * 4 + q;  // == b
      const float* crow = comb + row * 512;
      float s = 0.f;
#pragma unroll
      for (int jn = 0; jn < 8; ++jn) {
        const int col = obase + jn * 16;
        const float x = acc[i][jn][q] + crow[col];
        s += fast_tanh(x) * Wo[col];
      }
      ps[i][q] = s;
    }
  }
#pragma unroll
  for (int i = 0; i < 2; ++i)
#pragma unroll
    for (int q = 0; q < 4; ++q) {
      float s = ps[i][q];
      s += __shfl_xor(s, 1, 16);
      s += __shfl_xor(s, 2, 16);
      s += __shfl_xor(s, 4, 16);
      s += __shfl_xor(s, 8, 16);
      if (l15 == 0) spart[wn][wm * 32 + i * 16 + lq * 4 + q] = s;
    }
  __syncthreads();
  if (tid < 64) {
    float s = spart[0][tid] + spart[1][tid] + spart[2][tid] + spart[3][tid];
    scores[(long)tid * 2048 + blockIdx.x] = s;  // scores[b][t], t = blockIdx
  }
}

// ---------------- masked softmax over valid prefix ---------------------------
__global__ void softmax_kernel(const float* __restrict__ scores,
                               const int* __restrict__ enc_len,
                               float* __restrict__ out) {
  const int b = blockIdx.x;
  const int tid = threadIdx.x;  // 256
  const int lane = tid & 63;
  const int wv = tid >> 6;
  __shared__ float red[4];
  const int n = enc_len[b];
  const float* sc = scores + (long)b * 2048;

  float v[8];
  float m = -1e30f;
#pragma unroll
  for (int j = 0; j < 8; ++j) {
    const int t = tid + j * 256;
    v[j] = sc[t];
    if (t < n) m = fmaxf(m, v[j]);
  }
#pragma unroll
  for (int k = 32; k; k >>= 1) m = fmaxf(m, __shfl_xor(m, k, 64));
  if (lane == 0) red[wv] = m;
  __syncthreads();
  m = fmaxf(fmaxf(red[0], red[1]), fmaxf(red[2], red[3]));
  __syncthreads();

  float s = 0.f;
#pragma unroll
  for (int j = 0; j < 8; ++j) {
    const int t = tid + j * 256;
    const float e = (t < n) ? __expf(v[j] - m) : 0.f;
    v[j] = e;
    s += e;
  }
#pragma unroll
  for (int k = 32; k; k >>= 1) s += __shfl_xor(s, k, 64);
  if (lane == 0) red[wv] = s;
  __syncthreads();
  s = red[0] + red[1] + red[2] + red[3];
  const float inv = 1.0f / s;
#pragma unroll
  for (int j = 0; j < 8; ++j) {
    const int t = tid + j * 256;
    out[(long)b * 2048 + t] = v[j] * inv;
  }
}

extern "C" void kernel_launch(void* const* d_in, const int* in_sizes, int n_in,
                              void* d_out, int out_size, void* d_ws, size_t ws_size,
                              hipStream_t stream) {
  const float* hidden = (const float*)d_in[0];   // [2,64,512]
  const float* enc    = (const float*)d_in[1];   // [2048,64,512]
  const int*   enclen = (const int*)d_in[2];     // [64]
  const float* Wh     = (const float*)d_in[3];   // [512,512]
  const float* bh     = (const float*)d_in[4];   // [512]
  const float* We     = (const float*)d_in[5];   // [512,512]
  const float* be     = (const float*)d_in[6];   // [512]
  const float* Wo     = (const float*)d_in[7];   // [512]
  // d_in[8] = bo: softmax-invariant, dropped
  float* out = (float*)d_out;

  uint8_t* ws = (uint8_t*)d_ws;
  unsigned short* wsw = (unsigned short*)ws;             // 512 KB
  float* comb   = (float*)(ws + 524288);                 // 128 KB
  float* scores = (float*)(ws + 524288 + 131072);        // 512 KB

  hipLaunchKernelGGL(prep_comb_kernel, dim3(64), dim3(256), 0, stream,
                     hidden, Wh, bh, be, comb);
  hipLaunchKernelGGL(prep_pack_kernel, dim3(128), dim3(256), 0, stream, We, wsw);
  hipLaunchKernelGGL(gemm_score_kernel, dim3(2048), dim3(512), 0, stream,
                     enc, wsw, comb, Wo, scores);
  hipLaunchKernelGGL(softmax_kernel, dim3(64), dim3(256), 0, stream,
                     scores, enclen, out);
}